// Round 14
// baseline (269.723 us; speedup 1.0000x reference)
//
#include <hip/hip_runtime.h>
#include <math.h>

#define N_NODES 100000
#define F_IN    512
#define HIDDEN  64
#define N_CLASS 40
#define N_EDGES 3200000
#define NB      782          // ceil(N_NODES/128) buckets of 128 dst nodes
#define CAP     6144         // per-bucket capacity (mean 4096, sigma 64 -> 32 sigma margin)
#define EPB     8192         // edges per block in partition pass1
#define NPB     391          // ceil(N_EDGES/EPB)

typedef int EIdx;

typedef __attribute__((ext_vector_type(8))) short short8;
typedef __attribute__((ext_vector_type(4))) float f32x4;
typedef __attribute__((ext_vector_type(4))) unsigned uint4v;

__device__ inline short f2bf(float f) {
    unsigned u = __builtin_bit_cast(unsigned, f);
    unsigned r = u + 0x7FFFu + ((u >> 16) & 1u);   // round-to-nearest-even
    return (short)(r >> 16);
}

__device__ inline unsigned cvtpk(float lo, float hi) {
    unsigned r;
    asm("v_cvt_pk_bf16_f32 %0, %1, %2" : "=v"(r) : "v"(lo), "v"(hi));
    return r;
}

__device__ inline float bflo(unsigned w) { return __builtin_bit_cast(float, w << 16); }
__device__ inline float bfhi(unsigned w) { return __builtin_bit_cast(float, w & 0xFFFF0000u); }

// ---------------- W1 -> bf16 swizzled + bucket cursor init (fused) ----------------
__global__ __launch_bounds__(256) void wprep_kernel(const float* __restrict__ W,
                                                    short* __restrict__ Wbf,
                                                    int* __restrict__ bcur) {
    int idx = blockIdx.x * 256 + threadIdx.x;   // 32768 exactly
    if (idx < NB) bcur[idx] = idx * CAP;
    int k = idx >> 6, col = idx & 63;           // W is [k][col], read coalesced
    Wbf[col * F_IN + (k ^ ((col & 7) << 3))] = f2bf(W[idx]);
}

// ---------------- pass1: scatter edges into strided buckets (LDS staged) ----------------
// packed entry: (dlocal<<20) | src   (src < 2^17, dlocal < 2^7)
__global__ __launch_bounds__(256) void part1_kernel(const EIdx* __restrict__ src,
                                                    const EIdx* __restrict__ dst,
                                                    int* __restrict__ bcur,
                                                    unsigned* __restrict__ bpacked) {
    __shared__ int hist[2 * NB];
    __shared__ int excl[NB];
    __shared__ int cur[2 * NB];
    __shared__ int delta[NB];
    __shared__ int stmp[256];
    __shared__ unsigned spk[EPB];          // 32 KiB
    __shared__ unsigned short bid[EPB];    // 16 KiB
    int t = threadIdx.x;
    int sub = t >> 7;                      // wave-pair id (0 or 1)
    int e0 = blockIdx.x * EPB;
    int dreg[32];
    for (int j = t; j < 2 * NB; j += 256) hist[j] = 0;
    __syncthreads();
#pragma unroll
    for (int k = 0; k < 32; ++k) {
        int e = e0 + k * 256 + t;
        dreg[k] = (e < N_EDGES) ? dst[e] : -1;
        if (dreg[k] >= 0) atomicAdd(&hist[sub * NB + (dreg[k] >> 7)], 1);
    }
    __syncthreads();
    // exclusive scan of tot[0..NB): 4 bins/thread + one 256 ripple
    {
        int i0 = 4 * t;
        int v0 = (i0 < NB) ? hist[i0] + hist[NB + i0] : 0;
        int v1 = (i0 + 1 < NB) ? hist[i0 + 1] + hist[NB + i0 + 1] : 0;
        int v2 = (i0 + 2 < NB) ? hist[i0 + 2] + hist[NB + i0 + 2] : 0;
        int v3 = (i0 + 3 < NB) ? hist[i0 + 3] + hist[NB + i0 + 3] : 0;
        int s = v0 + v1 + v2 + v3;
        stmp[t] = s;
        __syncthreads();
        for (int o = 1; o < 256; o <<= 1) {
            int a = (t >= o) ? stmp[t - o] : 0;
            __syncthreads();
            stmp[t] += a;
            __syncthreads();
        }
        int E = stmp[t] - s;
        if (i0 < NB) excl[i0] = E;
        if (i0 + 1 < NB) excl[i0 + 1] = E + v0;
        if (i0 + 2 < NB) excl[i0 + 2] = E + v0 + v1;
        if (i0 + 3 < NB) excl[i0 + 3] = E + v0 + v1 + v2;
    }
    __syncthreads();
    // reserve contiguous ranges inside each bucket's strided region
    for (int j = t; j < NB; j += 256) {
        int h0 = hist[j], h1 = hist[NB + j];
        int tot = h0 + h1;
        int rsv = tot ? atomicAdd(&bcur[j], tot) : 0;
        delta[j] = rsv - excl[j];
        cur[j] = excl[j];              // sub 0 region
        cur[NB + j] = excl[j] + h0;    // sub 1 region
    }
    __syncthreads();
    // scatter into LDS, sorted by bucket (dst from regs, src fresh)
#pragma unroll
    for (int k = 0; k < 32; ++k) {
        int d = dreg[k];
        if (d >= 0) {
            int e = e0 + k * 256 + t;
            int s = src[e];
            int b = d >> 7;
            int p = atomicAdd(&cur[sub * NB + b], 1);
            spk[p] = ((unsigned)(d & 127) << 20) | (unsigned)s;
            bid[p] = (unsigned short)b;
        }
    }
    __syncthreads();
    // write out: consecutive i within a bucket -> consecutive global addresses
    int cnt = N_EDGES - e0;
    if (cnt > EPB) cnt = EPB;
    for (int i = t; i < cnt; i += 256) {
        int bb = bid[i];
        int pos = i + delta[bb];
        if (pos < (bb + 1) * CAP) bpacked[pos] = spk[i];   // clamp guard (never hit)
    }
}

// ---------------- pass2: per-bucket sort by node; emit csr_src, rowmeta, dis ----------------
__global__ __launch_bounds__(256) void part2_kernel(const int* __restrict__ bcur,
                                                    const unsigned* __restrict__ bpacked,
                                                    int* __restrict__ csr_src,
                                                    unsigned* __restrict__ rowmeta,
                                                    float* __restrict__ dis) {
    __shared__ unsigned ent[CAP];   // 24 KiB
    __shared__ int hist[2 * 128];
    __shared__ int stmp[128];
    __shared__ int cur[2 * 128];
    int t = threadIdx.x;
    int sub = t >> 7;
    int bk = blockIdx.x;
    int base = bk * CAP;
    int cnt = bcur[bk] - base;
    if (cnt > CAP) cnt = CAP;
    hist[t] = 0;
    __syncthreads();
    for (int i = t; i < cnt; i += 256) {
        unsigned p = bpacked[base + i];
        ent[i] = p;
        atomicAdd(&hist[sub * 128 + (p >> 20)], 1);
    }
    __syncthreads();
    if (t < 128) stmp[t] = hist[t] + hist[128 + t];
    __syncthreads();
    for (int o = 1; o < 128; o <<= 1) {
        int a = (t >= o && t < 128) ? stmp[t - o] : 0;
        __syncthreads();
        if (t < 128) stmp[t] += a;
        __syncthreads();
    }
    if (t < 128) {
        int tot = hist[t] + hist[128 + t];
        int ex = stmp[t] - tot;       // exclusive
        cur[t] = ex;                  // sub 0
        cur[128 + t] = ex + hist[t];  // sub 1
        int n = (bk << 7) + t;
        if (n < N_NODES) {
            rowmeta[n] = (unsigned)(base + ex) | ((unsigned)tot << 23);
            dis[n] = rsqrtf((float)(tot + 1));   // +1 self-loop
        }
    }
    __syncthreads();
    for (int i = t; i < cnt; i += 256) {
        unsigned p = ent[i];
        int p2 = atomicAdd(&cur[sub * 128 + (p >> 20)], 1);
        csr_src[base + p2] = (int)(p & 0xFFFFFu);
    }
}

// ---------------- GEMM1 (MFMA bf16), TLP-max: M=64 rows/block, ~21.5 KB LDS ----------------
// 1563 blocks, 7 blocks/CU. Wave w owns rows r0+w*16..+16, all 64 cols. 16 K-steps of 32.
__global__ __launch_bounds__(256) void gemm1_mfma_kernel(const float* __restrict__ x,
                                                         const short* __restrict__ Wbf,
                                                         const float* __restrict__ dis,
                                                         unsigned* __restrict__ h1b) {
    __shared__ short Wt[HIDDEN * 128];  // 16 KiB: quarter of W, [col][128k] swizzled
    __shared__ short xs[64 * 40];       // 5 KiB:  [row][32k + 8 pad] bf16
    int tid = threadIdx.x;
    int wave = tid >> 6, lane = tid & 63;
    int r0 = blockIdx.x * 64;
    int wr0 = r0 + wave * 16;
    int lrow = lane & 15;
    int lk = (lane >> 4) * 8;
    int bswz = (lane & 7) << 3;

    f32x4 acc[4];
#pragma unroll
    for (int n = 0; n < 4; ++n) acc[n] = (f32x4)0.0f;

    // staging geometry: 4 threads per row, each stages 8 floats (2 float4)
    int srow = tid >> 2;      // 0..63
    int schunk = tid & 3;     // 8-float chunk within the 32-k step
    int grow = r0 + srow;
    if (grow >= N_NODES) grow = N_NODES - 1;
    const float* gp = x + (size_t)grow * F_IN + schunk * 8;

    float4 xr0 = *reinterpret_cast<const float4*>(gp);
    float4 xr1 = *reinterpret_cast<const float4*>(gp + 4);

    const short8* Wv = (const short8*)Wbf;
    short8* Lv = (short8*)Wt;

    for (int ks = 0; ks < 16; ++ks) {       // 16 steps of 32 k
        __syncthreads();                    // xs consumed by previous step
        {
            uint4v u = {cvtpk(xr0.x, xr0.y), cvtpk(xr0.z, xr0.w),
                        cvtpk(xr1.x, xr1.y), cvtpk(xr1.z, xr1.w)};
            *reinterpret_cast<uint4v*>(&xs[srow * 40 + schunk * 8]) = u;
        }
        if ((ks & 3) == 0) {                // stage W quarter q = ks>>2
            int q = ks >> 2;
            for (int i = tid; i < 1024; i += 256) {
                int col = i >> 4, kc = i & 15;
                Lv[i] = Wv[col * 64 + q * 16 + kc];
            }
        }
        __syncthreads();
        if (ks < 15) {                      // prefetch next step
            int kn = (ks + 1) * 32;
            xr0 = *reinterpret_cast<const float4*>(gp + kn);
            xr1 = *reinterpret_cast<const float4*>(gp + kn + 4);
        }
        int klocq = (ks & 3) * 32;          // k offset within staged quarter
        short8 a0 = *reinterpret_cast<const short8*>(&xs[(wave * 16 + lrow) * 40 + lk]);
        short8 b[4];
#pragma unroll
        for (int n = 0; n < 4; ++n) {
            int c = n * 16 + lrow;
            b[n] = *reinterpret_cast<const short8*>(&Wt[c * 128 + ((klocq + lk) ^ bswz)]);
        }
#pragma unroll
        for (int n = 0; n < 4; ++n)
            acc[n] = __builtin_amdgcn_mfma_f32_16x16x32_bf16(a0, b[n], acc[n], 0, 0, 0);
    }

    // C layout: col = lane&15, row = (lane>>4)*4 + reg; pack bf16 pairs via shfl_xor(1)
    int crow = (lane >> 4) * 4, ccol = lane & 15;
    bool evenc = (ccol & 1) == 0;
#pragma unroll
    for (int j = 0; j < 4; ++j) {
        int rr = wr0 + crow + j;
        int rs = (rr < N_NODES) ? rr : (N_NODES - 1);
        float ds = dis[rs];
        float v[4], vn[4];
#pragma unroll
        for (int n = 0; n < 4; ++n) v[n] = acc[n][j] * ds;
#pragma unroll
        for (int n = 0; n < 4; ++n) vn[n] = __shfl_xor(v[n], 1);
        if (rr < N_NODES && evenc) {
#pragma unroll
            for (int n = 0; n < 4; ++n)
                h1b[(size_t)rr * 32 + ((n * 16 + ccol) >> 1)] = cvtpk(v[n], vn[n]);
        }
    }
}

// ---- fused layer-1 gather + GEMM2: 32 nodes/block, 8-lane groups, parallel gemm2 ----
__global__ __launch_bounds__(256) void gather1_gemm2_kernel(const unsigned* __restrict__ h1b,
                                                            const unsigned* __restrict__ rowmeta,
                                                            const int* __restrict__ csr_src,
                                                            const float* __restrict__ dis,
                                                            const float* __restrict__ b1,
                                                            const float* __restrict__ W2,
                                                            unsigned* __restrict__ h2b) {
    __shared__ float W2s[HIDDEN * N_CLASS];   // 10 KiB [k][c]
    __shared__ float aggs[32 * HIDDEN];       // 8 KiB  [node][feat]
    __shared__ float outs[32 * N_CLASS];      // 5 KiB  [node][class]
    int tid = threadIdx.x;
    for (int i = tid; i < HIDDEN * N_CLASS; i += 256) W2s[i] = W2[i];   // coalesced

    int nl = tid >> 3;                      // node-local 0..31
    int n = blockIdx.x * 32 + nl;
    int l = tid & 7;                        // lane owns features 8l..8l+7
    unsigned meta = rowmeta[n];
    int base = (int)(meta & 0x7FFFFFu);
    int deg = (int)(meta >> 23);
    const unsigned* rowp = h1b + 4 * l;
    uint4 v = *reinterpret_cast<const uint4*>(h1b + (size_t)n * 32 + 4 * l);
    float a0 = bflo(v.x), a1 = bfhi(v.x), a2 = bflo(v.y), a3 = bfhi(v.y);
    float a4 = bflo(v.z), a5 = bfhi(v.z), a6 = bflo(v.w), a7 = bfhi(v.w);
    int e = 0;
    for (; e + 7 < deg; e += 8) {           // 8-deep unroll: 8 loads in flight
        int s0 = csr_src[base + e],     s1 = csr_src[base + e + 1];
        int s2 = csr_src[base + e + 2], s3 = csr_src[base + e + 3];
        int s4 = csr_src[base + e + 4], s5 = csr_src[base + e + 5];
        int s6 = csr_src[base + e + 6], s7 = csr_src[base + e + 7];
        uint4 r0 = *reinterpret_cast<const uint4*>(rowp + (size_t)s0 * 32);
        uint4 r1 = *reinterpret_cast<const uint4*>(rowp + (size_t)s1 * 32);
        uint4 r2 = *reinterpret_cast<const uint4*>(rowp + (size_t)s2 * 32);
        uint4 r3 = *reinterpret_cast<const uint4*>(rowp + (size_t)s3 * 32);
        uint4 r4 = *reinterpret_cast<const uint4*>(rowp + (size_t)s4 * 32);
        uint4 r5 = *reinterpret_cast<const uint4*>(rowp + (size_t)s5 * 32);
        uint4 r6 = *reinterpret_cast<const uint4*>(rowp + (size_t)s6 * 32);
        uint4 r7 = *reinterpret_cast<const uint4*>(rowp + (size_t)s7 * 32);
        a0 += ((bflo(r0.x) + bflo(r1.x)) + (bflo(r2.x) + bflo(r3.x))) +
              ((bflo(r4.x) + bflo(r5.x)) + (bflo(r6.x) + bflo(r7.x)));
        a1 += ((bfhi(r0.x) + bfhi(r1.x)) + (bfhi(r2.x) + bfhi(r3.x))) +
              ((bfhi(r4.x) + bfhi(r5.x)) + (bfhi(r6.x) + bfhi(r7.x)));
        a2 += ((bflo(r0.y) + bflo(r1.y)) + (bflo(r2.y) + bflo(r3.y))) +
              ((bflo(r4.y) + bflo(r5.y)) + (bflo(r6.y) + bflo(r7.y)));
        a3 += ((bfhi(r0.y) + bfhi(r1.y)) + (bfhi(r2.y) + bfhi(r3.y))) +
              ((bfhi(r4.y) + bfhi(r5.y)) + (bfhi(r6.y) + bfhi(r7.y)));
        a4 += ((bflo(r0.z) + bflo(r1.z)) + (bflo(r2.z) + bflo(r3.z))) +
              ((bflo(r4.z) + bflo(r5.z)) + (bflo(r6.z) + bflo(r7.z)));
        a5 += ((bfhi(r0.z) + bfhi(r1.z)) + (bfhi(r2.z) + bfhi(r3.z))) +
              ((bfhi(r4.z) + bfhi(r5.z)) + (bfhi(r6.z) + bfhi(r7.z)));
        a6 += ((bflo(r0.w) + bflo(r1.w)) + (bflo(r2.w) + bflo(r3.w))) +
              ((bflo(r4.w) + bflo(r5.w)) + (bflo(r6.w) + bflo(r7.w)));
        a7 += ((bfhi(r0.w) + bfhi(r1.w)) + (bfhi(r2.w) + bfhi(r3.w))) +
              ((bfhi(r4.w) + bfhi(r5.w)) + (bfhi(r6.w) + bfhi(r7.w)));
    }
    for (; e < deg; ++e) {
        int s = csr_src[base + e];
        uint4 r = *reinterpret_cast<const uint4*>(rowp + (size_t)s * 32);
        a0 += bflo(r.x); a1 += bfhi(r.x); a2 += bflo(r.y); a3 += bfhi(r.y);
        a4 += bflo(r.z); a5 += bfhi(r.z); a6 += bflo(r.w); a7 += bfhi(r.w);
    }
    float ds = dis[n];
    {   // bias + relu -> LDS aggs
        float4 bL = *reinterpret_cast<const float4*>(b1 + 8 * l);
        float4 bH = *reinterpret_cast<const float4*>(b1 + 8 * l + 4);
        float4 oL = {fmaxf(fmaf(a0, ds, bL.x), 0.f), fmaxf(fmaf(a1, ds, bL.y), 0.f),
                     fmaxf(fmaf(a2, ds, bL.z), 0.f), fmaxf(fmaf(a3, ds, bL.w), 0.f)};
        float4 oH = {fmaxf(fmaf(a4, ds, bH.x), 0.f), fmaxf(fmaf(a5, ds, bH.y), 0.f),
                     fmaxf(fmaf(a6, ds, bH.z), 0.f), fmaxf(fmaf(a7, ds, bH.w), 0.f)};
        float* ap = aggs + nl * HIDDEN + 8 * l;
        *reinterpret_cast<float4*>(ap) = oL;
        *reinterpret_cast<float4*>(ap + 4) = oH;
    }
    __syncthreads();   // aggs + W2s ready
    // gemm2 phase: thread (nl, l) computes classes 5l..5l+4 for node nl, k ascending
    {
        float o0 = 0.f, o1 = 0.f, o2 = 0.f, o3 = 0.f, o4 = 0.f;
        const float* ar = aggs + nl * HIDDEN;
        int c0 = 5 * l;
#pragma unroll 8
        for (int k = 0; k < HIDDEN; ++k) {
            float av = ar[k];
            const float* wr = W2s + k * N_CLASS + c0;
            o0 = fmaf(av, wr[0], o0);
            o1 = fmaf(av, wr[1], o1);
            o2 = fmaf(av, wr[2], o2);
            o3 = fmaf(av, wr[3], o3);
            o4 = fmaf(av, wr[4], o4);
        }
        float* op = outs + nl * N_CLASS + c0;
        op[0] = o0 * ds; op[1] = o1 * ds; op[2] = o2 * ds; op[3] = o3 * ds; op[4] = o4 * ds;
    }
    __syncthreads();
    // pack phase: 640 u32 words (32 nodes x 20)
    for (int i = tid; i < 32 * 20; i += 256) {
        int n3 = i / 20, c3 = i % 20;
        const float* op = outs + n3 * N_CLASS + 2 * c3;
        h2b[(size_t)(blockIdx.x * 32 + n3) * 20 + c3] = cvtpk(op[0], op[1]);
    }
}

// ---------------- layer-2 gather + log_softmax: 8-lane group per node (5 active) ----------------
__global__ __launch_bounds__(256) void gather2_kernel(const unsigned* __restrict__ h2b,
                                                      const unsigned* __restrict__ rowmeta,
                                                      const int* __restrict__ csr_src,
                                                      const float* __restrict__ dis,
                                                      const float* __restrict__ b2,
                                                      float* __restrict__ xout,
                                                      float* __restrict__ out_ls) {
    int tid = threadIdx.x;
    int n = blockIdx.x * 32 + (tid >> 3);
    int l = tid & 7;
    bool act = l < 5;                      // lane owns classes 8l..8l+7 (l<5)
    unsigned meta = rowmeta[n];
    int base = (int)(meta & 0x7FFFFFu);
    int deg = (int)(meta >> 23);
    const unsigned* rowp = h2b + 4 * l;
    float a0 = 0.f, a1 = 0.f, a2 = 0.f, a3 = 0.f, a4 = 0.f, a5 = 0.f, a6 = 0.f, a7 = 0.f;
    if (act) {
        uint4 v = *reinterpret_cast<const uint4*>(h2b + (size_t)n * 20 + 4 * l);
        a0 = bflo(v.x); a1 = bfhi(v.x); a2 = bflo(v.y); a3 = bfhi(v.y);
        a4 = bflo(v.z); a5 = bfhi(v.z); a6 = bflo(v.w); a7 = bfhi(v.w);
    }
    int e = 0;
    for (; e + 7 < deg; e += 8) {
        int s0 = csr_src[base + e],     s1 = csr_src[base + e + 1];
        int s2 = csr_src[base + e + 2], s3 = csr_src[base + e + 3];
        int s4 = csr_src[base + e + 4], s5 = csr_src[base + e + 5];
        int s6 = csr_src[base + e + 6], s7 = csr_src[base + e + 7];
        if (act) {
            uint4 r0 = *reinterpret_cast<const uint4*>(rowp + (size_t)s0 * 20);
            uint4 r1 = *reinterpret_cast<const uint4*>(rowp + (size_t)s1 * 20);
            uint4 r2 = *reinterpret_cast<const uint4*>(rowp + (size_t)s2 * 20);
            uint4 r3 = *reinterpret_cast<const uint4*>(rowp + (size_t)s3 * 20);
            uint4 r4 = *reinterpret_cast<const uint4*>(rowp + (size_t)s4 * 20);
            uint4 r5 = *reinterpret_cast<const uint4*>(rowp + (size_t)s5 * 20);
            uint4 r6 = *reinterpret_cast<const uint4*>(rowp + (size_t)s6 * 20);
            uint4 r7 = *reinterpret_cast<const uint4*>(rowp + (size_t)s7 * 20);
            a0 += ((bflo(r0.x) + bflo(r1.x)) + (bflo(r2.x) + bflo(r3.x))) +
                  ((bflo(r4.x) + bflo(r5.x)) + (bflo(r6.x) + bflo(r7.x)));
            a1 += ((bfhi(r0.x) + bfhi(r1.x)) + (bfhi(r2.x) + bfhi(r3.x))) +
                  ((bfhi(r4.x) + bfhi(r5.x)) + (bfhi(r6.x) + bfhi(r7.x)));
            a2 += ((bflo(r0.y) + bflo(r1.y)) + (bflo(r2.y) + bflo(r3.y))) +
                  ((bflo(r4.y) + bflo(r5.y)) + (bflo(r6.y) + bflo(r7.y)));
            a3 += ((bfhi(r0.y) + bfhi(r1.y)) + (bfhi(r2.y) + bfhi(r3.y))) +
                  ((bfhi(r4.y) + bfhi(r5.y)) + (bfhi(r6.y) + bfhi(r7.y)));
            a4 += ((bflo(r0.z) + bflo(r1.z)) + (bflo(r2.z) + bflo(r3.z))) +
                  ((bflo(r4.z) + bflo(r5.z)) + (bflo(r6.z) + bflo(r7.z)));
            a5 += ((bfhi(r0.z) + bfhi(r1.z)) + (bfhi(r2.z) + bfhi(r3.z))) +
                  ((bfhi(r4.z) + bfhi(r5.z)) + (bfhi(r6.z) + bfhi(r7.z)));
            a6 += ((bflo(r0.w) + bflo(r1.w)) + (bflo(r2.w) + bflo(r3.w))) +
                  ((bflo(r4.w) + bflo(r5.w)) + (bflo(r6.w) + bflo(r7.w)));
            a7 += ((bfhi(r0.w) + bfhi(r1.w)) + (bfhi(r2.w) + bfhi(r3.w))) +
                  ((bfhi(r4.w) + bfhi(r5.w)) + (bfhi(r6.w) + bfhi(r7.w)));
        }
    }
    for (; e < deg; ++e) {
        int s = csr_src[base + e];
        if (act) {
            uint4 r = *reinterpret_cast<const uint4*>(rowp + (size_t)s * 20);
            a0 += bflo(r.x); a1 += bfhi(r.x); a2 += bflo(r.y); a3 += bfhi(r.y);
            a4 += bflo(r.z); a5 += bfhi(r.z); a6 += bflo(r.w); a7 += bfhi(r.w);
        }
    }
    float ds = dis[n];
    float v0 = 0.f, v1 = 0.f, v2 = 0.f, v3 = 0.f, v4 = 0.f, v5 = 0.f, v6 = 0.f, v7 = 0.f;
    if (act) {
        float4 bL = *reinterpret_cast<const float4*>(b2 + 8 * l);
        float4 bH = *reinterpret_cast<const float4*>(b2 + 8 * l + 4);
        v0 = fmaf(a0, ds, bL.x); v1 = fmaf(a1, ds, bL.y);
        v2 = fmaf(a2, ds, bL.z); v3 = fmaf(a3, ds, bL.w);
        v4 = fmaf(a4, ds, bH.x); v5 = fmaf(a5, ds, bH.y);
        v6 = fmaf(a6, ds, bH.z); v7 = fmaf(a7, ds, bH.w);
    }
    float mx = act ? fmaxf(fmaxf(fmaxf(v0, v1), fmaxf(v2, v3)),
                           fmaxf(fmaxf(v4, v5), fmaxf(v6, v7))) : -INFINITY;
    mx = fmaxf(mx, __shfl_xor(mx, 1));
    mx = fmaxf(mx, __shfl_xor(mx, 2));
    mx = fmaxf(mx, __shfl_xor(mx, 4));
    float sum = act ? ((expf(v0 - mx) + expf(v1 - mx)) + (expf(v2 - mx) + expf(v3 - mx))) +
                      ((expf(v4 - mx) + expf(v5 - mx)) + (expf(v6 - mx) + expf(v7 - mx))) : 0.f;
    sum += __shfl_xor(sum, 1);
    sum += __shfl_xor(sum, 2);
    sum += __shfl_xor(sum, 4);
    if (act) {
        float ls = mx + logf(sum);
        float* xp = xout + (size_t)n * N_CLASS + 8 * l;
        float* lp = out_ls + (size_t)n * N_CLASS + 8 * l;
        float4 xoL = {v0, v1, v2, v3};
        float4 xoH = {v4, v5, v6, v7};
        float4 loL = {v0 - ls, v1 - ls, v2 - ls, v3 - ls};
        float4 loH = {v4 - ls, v5 - ls, v6 - ls, v7 - ls};
        *reinterpret_cast<float4*>(xp) = xoL;
        *reinterpret_cast<float4*>(xp + 4) = xoH;
        *reinterpret_cast<float4*>(lp) = loL;
        *reinterpret_cast<float4*>(lp + 4) = loH;
    }
}

extern "C" void kernel_launch(void* const* d_in, const int* in_sizes, int n_in,
                              void* d_out, int out_size, void* d_ws, size_t ws_size,
                              hipStream_t stream) {
    const float* x  = (const float*)d_in[0];
    const EIdx*  ei = (const EIdx*)d_in[1];
    const float* W1 = (const float*)d_in[2];
    const float* b1 = (const float*)d_in[3];
    const float* W2 = (const float*)d_in[4];
    const float* b2 = (const float*)d_in[5];
    const EIdx* src = ei;
    const EIdx* dst = ei + N_EDGES;

    float* out_ls = (float*)d_out;                        // [N, 40] log_softmax
    float* x_out  = out_ls + (size_t)N_NODES * N_CLASS;   // [N, 40]

    char* w = (char*)d_ws;
    int*      bcur    = (int*)w;       w += 1024 * 4;
    float*    dis     = (float*)w;     w += 100352 * 4;
    unsigned* rowmeta = (unsigned*)w;  w += 100352 * 4;
    short*    Wbf     = (short*)w;     w += (size_t)F_IN * HIDDEN * 2;
    unsigned* bpacked = (unsigned*)w;  w += (size_t)NB * CAP * 4;        // 19.2 MB
    int*      csr_src = (int*)w;       w += (size_t)NB * CAP * 4;        // 19.2 MB
    unsigned* h1b     = (unsigned*)w;  w += (size_t)N_NODES * 32 * 4;    // 12.8 MB
    unsigned* h2b     = (unsigned*)w;  w += (size_t)N_NODES * 20 * 4;    // 8 MB

    const int B = 256;
    int gG  = N_NODES / 32;              // 3125 (8-lane group per node)
    int gM1 = (N_NODES + 63) / 64;       // 1563

    // W prep + bucket cursor init, then CSR build
    wprep_kernel<<<(F_IN * HIDDEN) / B, B, 0, stream>>>(W1, Wbf, bcur);
    part1_kernel<<<NPB, B, 0, stream>>>(src, dst, bcur, bpacked);
    part2_kernel<<<NB, B, 0, stream>>>(bcur, bpacked, csr_src, rowmeta, dis);

    // layer 1
    gemm1_mfma_kernel<<<gM1, B, 0, stream>>>(x, Wbf, dis, h1b);
    gather1_gemm2_kernel<<<gG, B, 0, stream>>>(h1b, rowmeta, csr_src, dis, b1, W2, h2b);

    // layer 2 aggregation + log_softmax
    gather2_kernel<<<gG, B, 0, stream>>>(h2b, rowmeta, csr_src, dis, b2, x_out, out_ls);
}

// Round 15
// 263.048 us; speedup vs baseline: 1.0254x; 1.0254x over previous
//
#include <hip/hip_runtime.h>
#include <math.h>

#define N_NODES 100000
#define F_IN    512
#define HIDDEN  64
#define N_CLASS 40
#define N_EDGES 3200000
#define NB      782          // ceil(N_NODES/128) buckets of 128 dst nodes
#define CAP     6144         // per-bucket capacity (mean 4096, sigma 64 -> 32 sigma margin)
#define EPB     8192         // edges per block in partition pass1
#define NPB     391          // ceil(N_EDGES/EPB)

typedef int EIdx;

typedef __attribute__((ext_vector_type(8))) short short8;
typedef __attribute__((ext_vector_type(4))) float f32x4;
typedef __attribute__((ext_vector_type(4))) unsigned uint4v;

__device__ inline short f2bf(float f) {
    unsigned u = __builtin_bit_cast(unsigned, f);
    unsigned r = u + 0x7FFFu + ((u >> 16) & 1u);   // round-to-nearest-even
    return (short)(r >> 16);
}

__device__ inline unsigned cvtpk(float lo, float hi) {
    unsigned r;
    asm("v_cvt_pk_bf16_f32 %0, %1, %2" : "=v"(r) : "v"(lo), "v"(hi));
    return r;
}

__device__ inline float bflo(unsigned w) { return __builtin_bit_cast(float, w << 16); }
__device__ inline float bfhi(unsigned w) { return __builtin_bit_cast(float, w & 0xFFFF0000u); }

// ---------------- W1 -> bf16 swizzled + bucket cursor init (fused) ----------------
__global__ __launch_bounds__(256) void wprep_kernel(const float* __restrict__ W,
                                                    short* __restrict__ Wbf,
                                                    int* __restrict__ bcur) {
    int idx = blockIdx.x * 256 + threadIdx.x;   // 32768 exactly
    if (idx < NB) bcur[idx] = idx * CAP;
    int k = idx >> 6, col = idx & 63;           // W is [k][col], read coalesced
    Wbf[col * F_IN + (k ^ ((col & 7) << 3))] = f2bf(W[idx]);
}

// ---------------- pass1: scatter edges into strided buckets (LDS staged) ----------------
// packed entry: (dlocal<<20) | src   (src < 2^17, dlocal < 2^7)
__global__ __launch_bounds__(256) void part1_kernel(const EIdx* __restrict__ src,
                                                    const EIdx* __restrict__ dst,
                                                    int* __restrict__ bcur,
                                                    unsigned* __restrict__ bpacked) {
    __shared__ int hist[2 * NB];
    __shared__ int excl[NB];
    __shared__ int cur[2 * NB];
    __shared__ int delta[NB];
    __shared__ int stmp[256];
    __shared__ unsigned spk[EPB];          // 32 KiB
    __shared__ unsigned short bid[EPB];    // 16 KiB
    int t = threadIdx.x;
    int sub = t >> 7;                      // wave-pair id (0 or 1)
    int e0 = blockIdx.x * EPB;
    int dreg[32];
    for (int j = t; j < 2 * NB; j += 256) hist[j] = 0;
    __syncthreads();
#pragma unroll
    for (int k = 0; k < 32; ++k) {
        int e = e0 + k * 256 + t;
        dreg[k] = (e < N_EDGES) ? dst[e] : -1;
        if (dreg[k] >= 0) atomicAdd(&hist[sub * NB + (dreg[k] >> 7)], 1);
    }
    __syncthreads();
    // exclusive scan of tot[0..NB): 4 bins/thread + one 256 ripple
    {
        int i0 = 4 * t;
        int v0 = (i0 < NB) ? hist[i0] + hist[NB + i0] : 0;
        int v1 = (i0 + 1 < NB) ? hist[i0 + 1] + hist[NB + i0 + 1] : 0;
        int v2 = (i0 + 2 < NB) ? hist[i0 + 2] + hist[NB + i0 + 2] : 0;
        int v3 = (i0 + 3 < NB) ? hist[i0 + 3] + hist[NB + i0 + 3] : 0;
        int s = v0 + v1 + v2 + v3;
        stmp[t] = s;
        __syncthreads();
        for (int o = 1; o < 256; o <<= 1) {
            int a = (t >= o) ? stmp[t - o] : 0;
            __syncthreads();
            stmp[t] += a;
            __syncthreads();
        }
        int E = stmp[t] - s;
        if (i0 < NB) excl[i0] = E;
        if (i0 + 1 < NB) excl[i0 + 1] = E + v0;
        if (i0 + 2 < NB) excl[i0 + 2] = E + v0 + v1;
        if (i0 + 3 < NB) excl[i0 + 3] = E + v0 + v1 + v2;
    }
    __syncthreads();
    // reserve contiguous ranges inside each bucket's strided region
    for (int j = t; j < NB; j += 256) {
        int h0 = hist[j], h1 = hist[NB + j];
        int tot = h0 + h1;
        int rsv = tot ? atomicAdd(&bcur[j], tot) : 0;
        delta[j] = rsv - excl[j];
        cur[j] = excl[j];              // sub 0 region
        cur[NB + j] = excl[j] + h0;    // sub 1 region
    }
    __syncthreads();
    // scatter into LDS, sorted by bucket (dst from regs, src fresh)
#pragma unroll
    for (int k = 0; k < 32; ++k) {
        int d = dreg[k];
        if (d >= 0) {
            int e = e0 + k * 256 + t;
            int s = src[e];
            int b = d >> 7;
            int p = atomicAdd(&cur[sub * NB + b], 1);
            spk[p] = ((unsigned)(d & 127) << 20) | (unsigned)s;
            bid[p] = (unsigned short)b;
        }
    }
    __syncthreads();
    // write out: consecutive i within a bucket -> consecutive global addresses
    int cnt = N_EDGES - e0;
    if (cnt > EPB) cnt = EPB;
    for (int i = t; i < cnt; i += 256) {
        int bb = bid[i];
        int pos = i + delta[bb];
        if (pos < (bb + 1) * CAP) bpacked[pos] = spk[i];   // clamp guard (never hit)
    }
}

// ---------------- pass2: per-bucket sort by node; emit csr_src, rowmeta, dis ----------------
__global__ __launch_bounds__(256) void part2_kernel(const int* __restrict__ bcur,
                                                    const unsigned* __restrict__ bpacked,
                                                    int* __restrict__ csr_src,
                                                    unsigned* __restrict__ rowmeta,
                                                    float* __restrict__ dis) {
    __shared__ unsigned ent[CAP];   // 24 KiB
    __shared__ int hist[2 * 128];
    __shared__ int stmp[128];
    __shared__ int cur[2 * 128];
    int t = threadIdx.x;
    int sub = t >> 7;
    int bk = blockIdx.x;
    int base = bk * CAP;
    int cnt = bcur[bk] - base;
    if (cnt > CAP) cnt = CAP;
    hist[t] = 0;
    __syncthreads();
    for (int i = t; i < cnt; i += 256) {
        unsigned p = bpacked[base + i];
        ent[i] = p;
        atomicAdd(&hist[sub * 128 + (p >> 20)], 1);
    }
    __syncthreads();
    if (t < 128) stmp[t] = hist[t] + hist[128 + t];
    __syncthreads();
    for (int o = 1; o < 128; o <<= 1) {
        int a = (t >= o && t < 128) ? stmp[t - o] : 0;
        __syncthreads();
        if (t < 128) stmp[t] += a;
        __syncthreads();
    }
    if (t < 128) {
        int tot = hist[t] + hist[128 + t];
        int ex = stmp[t] - tot;       // exclusive
        cur[t] = ex;                  // sub 0
        cur[128 + t] = ex + hist[t];  // sub 1
        int n = (bk << 7) + t;
        if (n < N_NODES) {
            rowmeta[n] = (unsigned)(base + ex) | ((unsigned)tot << 23);
            dis[n] = rsqrtf((float)(tot + 1));   // +1 self-loop
        }
    }
    __syncthreads();
    for (int i = t; i < cnt; i += 256) {
        unsigned p = ent[i];
        int p2 = atomicAdd(&cur[sub * 128 + (p >> 20)], 1);
        csr_src[base + p2] = (int)(p & 0xFFFFFu);
    }
}

// ---------------- GEMM1 (MFMA bf16): h1b = pack_bf16((x @ W1) * dis[row]) ----------------
// M=128, 8 steps of 64k, DEPTH-2 register prefetch (xrA/xrB) to cover ~900cy HBM latency.
__global__ __launch_bounds__(256) void gemm1_mfma_kernel(const float* __restrict__ x,
                                                         const short* __restrict__ Wbf,
                                                         const float* __restrict__ dis,
                                                         unsigned* __restrict__ h1b) {
    __shared__ short Wt[HIDDEN * 128];  // 16 KiB: quarter of W, [col][128k] swizzled
    __shared__ short xs[128 * 72];      // 18 KiB: [row][64k + 8 pad] bf16
    int tid = threadIdx.x;
    int wave = tid >> 6, lane = tid & 63;
    int r0 = blockIdx.x * 128;
    int wr0 = r0 + wave * 32;
    int lrow = lane & 15;
    int lk = (lane >> 4) * 8;
    int bswz = (lane & 7) << 3;

    f32x4 acc[2][4];
#pragma unroll
    for (int m = 0; m < 2; ++m)
#pragma unroll
        for (int n = 0; n < 4; ++n) acc[m][n] = (f32x4)0.0f;

    int srow = tid >> 4;      // 0..15, advances by 16 per i
    int schunk = tid & 15;    // float4 chunk within 64-k tile
    int grow[8];
#pragma unroll
    for (int i = 0; i < 8; ++i) {
        int r = r0 + srow + i * 16;
        grow[i] = (r < N_NODES) ? r : (N_NODES - 1);
    }

    // depth-2 prefetch: xrA holds step ks, xrB holds step ks+1
    float4 xrA[8], xrB[8];
#pragma unroll
    for (int i = 0; i < 8; ++i)
        xrA[i] = *reinterpret_cast<const float4*>(x + (size_t)grow[i] * F_IN + 4 * schunk);
#pragma unroll
    for (int i = 0; i < 8; ++i)
        xrB[i] = *reinterpret_cast<const float4*>(x + (size_t)grow[i] * F_IN + 64 + 4 * schunk);

    const short8* Wv = (const short8*)Wbf;
    short8* Lv = (short8*)Wt;

    for (int ks = 0; ks < 8; ks += 2) {
        // ---- even step ks (stages W quarter ks>>1, uses its first 64k half) ----
        __syncthreads();
#pragma unroll
        for (int i = 0; i < 8; ++i) {
            uint2 u = {cvtpk(xrA[i].x, xrA[i].y), cvtpk(xrA[i].z, xrA[i].w)};
            *reinterpret_cast<uint2*>(&xs[(srow + i * 16) * 72 + 4 * schunk]) = u;
        }
        {
            int q = ks >> 1;
            for (int i = tid; i < 1024; i += 256) {
                int col = i >> 4, kc = i & 15;
                Lv[i] = Wv[col * 64 + q * 16 + kc];
            }
        }
        __syncthreads();
        if (ks + 2 < 8) {
            int kn = (ks + 2) * 64;
#pragma unroll
            for (int i = 0; i < 8; ++i)
                xrA[i] = *reinterpret_cast<const float4*>(x + (size_t)grow[i] * F_IN + kn + 4 * schunk);
        }
#pragma unroll
        for (int s = 0; s < 2; ++s) {
            int kwq = s * 32;                   // even step: first half of quarter
            int kloc = s * 32;
            short8 a0 = *reinterpret_cast<const short8*>(&xs[(wave * 32 + lrow) * 72 + kloc + lk]);
            short8 a1 = *reinterpret_cast<const short8*>(&xs[(wave * 32 + 16 + lrow) * 72 + kloc + lk]);
            short8 b[4];
#pragma unroll
            for (int n = 0; n < 4; ++n) {
                int c = n * 16 + lrow;
                b[n] = *reinterpret_cast<const short8*>(&Wt[c * 128 + ((kwq + lk) ^ bswz)]);
            }
#pragma unroll
            for (int n = 0; n < 4; ++n) {
                acc[0][n] = __builtin_amdgcn_mfma_f32_16x16x32_bf16(a0, b[n], acc[0][n], 0, 0, 0);
                acc[1][n] = __builtin_amdgcn_mfma_f32_16x16x32_bf16(a1, b[n], acc[1][n], 0, 0, 0);
            }
        }
        // ---- odd step ks+1 (same W quarter, second 64k half) ----
        __syncthreads();
#pragma unroll
        for (int i = 0; i < 8; ++i) {
            uint2 u = {cvtpk(xrB[i].x, xrB[i].y), cvtpk(xrB[i].z, xrB[i].w)};
            *reinterpret_cast<uint2*>(&xs[(srow + i * 16) * 72 + 4 * schunk]) = u;
        }
        __syncthreads();
        if (ks + 3 < 8) {
            int kn = (ks + 3) * 64;
#pragma unroll
            for (int i = 0; i < 8; ++i)
                xrB[i] = *reinterpret_cast<const float4*>(x + (size_t)grow[i] * F_IN + kn + 4 * schunk);
        }
#pragma unroll
        for (int s = 0; s < 2; ++s) {
            int kwq = 64 + s * 32;              // odd step: second half of quarter
            int kloc = s * 32;
            short8 a0 = *reinterpret_cast<const short8*>(&xs[(wave * 32 + lrow) * 72 + kloc + lk]);
            short8 a1 = *reinterpret_cast<const short8*>(&xs[(wave * 32 + 16 + lrow) * 72 + kloc + lk]);
            short8 b[4];
#pragma unroll
            for (int n = 0; n < 4; ++n) {
                int c = n * 16 + lrow;
                b[n] = *reinterpret_cast<const short8*>(&Wt[c * 128 + ((kwq + lk) ^ bswz)]);
            }
#pragma unroll
            for (int n = 0; n < 4; ++n) {
                acc[0][n] = __builtin_amdgcn_mfma_f32_16x16x32_bf16(a0, b[n], acc[0][n], 0, 0, 0);
                acc[1][n] = __builtin_amdgcn_mfma_f32_16x16x32_bf16(a1, b[n], acc[1][n], 0, 0, 0);
            }
        }
    }

    // C layout: col = lane&15, row = (lane>>4)*4 + reg; pack bf16 pairs via shfl_xor(1)
    int crow = (lane >> 4) * 4, ccol = lane & 15;
    bool evenc = (ccol & 1) == 0;
#pragma unroll
    for (int m = 0; m < 2; ++m) {
#pragma unroll
        for (int j = 0; j < 4; ++j) {
            int rr = wr0 + m * 16 + crow + j;
            int rs = (rr < N_NODES) ? rr : (N_NODES - 1);
            float ds = dis[rs];
            float v[4], vn[4];
#pragma unroll
            for (int n = 0; n < 4; ++n) v[n] = acc[m][n][j] * ds;
#pragma unroll
            for (int n = 0; n < 4; ++n) vn[n] = __shfl_xor(v[n], 1);
            if (rr < N_NODES && evenc) {
#pragma unroll
                for (int n = 0; n < 4; ++n)
                    h1b[(size_t)rr * 32 + ((n * 16 + ccol) >> 1)] = cvtpk(v[n], vn[n]);
            }
        }
    }
}

// ---- fused layer-1 gather + GEMM2: 32 nodes/block, 8-lane groups, parallel gemm2 ----
__global__ __launch_bounds__(256) void gather1_gemm2_kernel(const unsigned* __restrict__ h1b,
                                                            const unsigned* __restrict__ rowmeta,
                                                            const int* __restrict__ csr_src,
                                                            const float* __restrict__ dis,
                                                            const float* __restrict__ b1,
                                                            const float* __restrict__ W2,
                                                            unsigned* __restrict__ h2b) {
    __shared__ float W2s[HIDDEN * N_CLASS];   // 10 KiB [k][c]
    __shared__ float aggs[32 * HIDDEN];       // 8 KiB  [node][feat]
    __shared__ float outs[32 * N_CLASS];      // 5 KiB  [node][class]
    int tid = threadIdx.x;
    for (int i = tid; i < HIDDEN * N_CLASS; i += 256) W2s[i] = W2[i];   // coalesced

    int nl = tid >> 3;                      // node-local 0..31
    int n = blockIdx.x * 32 + nl;
    int l = tid & 7;                        // lane owns features 8l..8l+7
    unsigned meta = rowmeta[n];
    int base = (int)(meta & 0x7FFFFFu);
    int deg = (int)(meta >> 23);
    const unsigned* rowp = h1b + 4 * l;
    uint4 v = *reinterpret_cast<const uint4*>(h1b + (size_t)n * 32 + 4 * l);
    float a0 = bflo(v.x), a1 = bfhi(v.x), a2 = bflo(v.y), a3 = bfhi(v.y);
    float a4 = bflo(v.z), a5 = bfhi(v.z), a6 = bflo(v.w), a7 = bfhi(v.w);
    int e = 0;
    for (; e + 7 < deg; e += 8) {           // 8-deep unroll: 8 loads in flight
        int s0 = csr_src[base + e],     s1 = csr_src[base + e + 1];
        int s2 = csr_src[base + e + 2], s3 = csr_src[base + e + 3];
        int s4 = csr_src[base + e + 4], s5 = csr_src[base + e + 5];
        int s6 = csr_src[base + e + 6], s7 = csr_src[base + e + 7];
        uint4 r0 = *reinterpret_cast<const uint4*>(rowp + (size_t)s0 * 32);
        uint4 r1 = *reinterpret_cast<const uint4*>(rowp + (size_t)s1 * 32);
        uint4 r2 = *reinterpret_cast<const uint4*>(rowp + (size_t)s2 * 32);
        uint4 r3 = *reinterpret_cast<const uint4*>(rowp + (size_t)s3 * 32);
        uint4 r4 = *reinterpret_cast<const uint4*>(rowp + (size_t)s4 * 32);
        uint4 r5 = *reinterpret_cast<const uint4*>(rowp + (size_t)s5 * 32);
        uint4 r6 = *reinterpret_cast<const uint4*>(rowp + (size_t)s6 * 32);
        uint4 r7 = *reinterpret_cast<const uint4*>(rowp + (size_t)s7 * 32);
        a0 += ((bflo(r0.x) + bflo(r1.x)) + (bflo(r2.x) + bflo(r3.x))) +
              ((bflo(r4.x) + bflo(r5.x)) + (bflo(r6.x) + bflo(r7.x)));
        a1 += ((bfhi(r0.x) + bfhi(r1.x)) + (bfhi(r2.x) + bfhi(r3.x))) +
              ((bfhi(r4.x) + bfhi(r5.x)) + (bfhi(r6.x) + bfhi(r7.x)));
        a2 += ((bflo(r0.y) + bflo(r1.y)) + (bflo(r2.y) + bflo(r3.y))) +
              ((bflo(r4.y) + bflo(r5.y)) + (bflo(r6.y) + bflo(r7.y)));
        a3 += ((bfhi(r0.y) + bfhi(r1.y)) + (bfhi(r2.y) + bfhi(r3.y))) +
              ((bfhi(r4.y) + bfhi(r5.y)) + (bfhi(r6.y) + bfhi(r7.y)));
        a4 += ((bflo(r0.z) + bflo(r1.z)) + (bflo(r2.z) + bflo(r3.z))) +
              ((bflo(r4.z) + bflo(r5.z)) + (bflo(r6.z) + bflo(r7.z)));
        a5 += ((bfhi(r0.z) + bfhi(r1.z)) + (bfhi(r2.z) + bfhi(r3.z))) +
              ((bfhi(r4.z) + bfhi(r5.z)) + (bfhi(r6.z) + bfhi(r7.z)));
        a6 += ((bflo(r0.w) + bflo(r1.w)) + (bflo(r2.w) + bflo(r3.w))) +
              ((bflo(r4.w) + bflo(r5.w)) + (bflo(r6.w) + bflo(r7.w)));
        a7 += ((bfhi(r0.w) + bfhi(r1.w)) + (bfhi(r2.w) + bfhi(r3.w))) +
              ((bfhi(r4.w) + bfhi(r5.w)) + (bfhi(r6.w) + bfhi(r7.w)));
    }
    for (; e < deg; ++e) {
        int s = csr_src[base + e];
        uint4 r = *reinterpret_cast<const uint4*>(rowp + (size_t)s * 32);
        a0 += bflo(r.x); a1 += bfhi(r.x); a2 += bflo(r.y); a3 += bfhi(r.y);
        a4 += bflo(r.z); a5 += bfhi(r.z); a6 += bflo(r.w); a7 += bfhi(r.w);
    }
    float ds = dis[n];
    {   // bias + relu -> LDS aggs
        float4 bL = *reinterpret_cast<const float4*>(b1 + 8 * l);
        float4 bH = *reinterpret_cast<const float4*>(b1 + 8 * l + 4);
        float4 oL = {fmaxf(fmaf(a0, ds, bL.x), 0.f), fmaxf(fmaf(a1, ds, bL.y), 0.f),
                     fmaxf(fmaf(a2, ds, bL.z), 0.f), fmaxf(fmaf(a3, ds, bL.w), 0.f)};
        float4 oH = {fmaxf(fmaf(a4, ds, bH.x), 0.f), fmaxf(fmaf(a5, ds, bH.y), 0.f),
                     fmaxf(fmaf(a6, ds, bH.z), 0.f), fmaxf(fmaf(a7, ds, bH.w), 0.f)};
        float* ap = aggs + nl * HIDDEN + 8 * l;
        *reinterpret_cast<float4*>(ap) = oL;
        *reinterpret_cast<float4*>(ap + 4) = oH;
    }
    __syncthreads();   // aggs + W2s ready
    // gemm2 phase: thread (nl, l) computes classes 5l..5l+4 for node nl, k ascending
    {
        float o0 = 0.f, o1 = 0.f, o2 = 0.f, o3 = 0.f, o4 = 0.f;
        const float* ar = aggs + nl * HIDDEN;
        int c0 = 5 * l;
#pragma unroll 8
        for (int k = 0; k < HIDDEN; ++k) {
            float av = ar[k];
            const float* wr = W2s + k * N_CLASS + c0;
            o0 = fmaf(av, wr[0], o0);
            o1 = fmaf(av, wr[1], o1);
            o2 = fmaf(av, wr[2], o2);
            o3 = fmaf(av, wr[3], o3);
            o4 = fmaf(av, wr[4], o4);
        }
        float* op = outs + nl * N_CLASS + c0;
        op[0] = o0 * ds; op[1] = o1 * ds; op[2] = o2 * ds; op[3] = o3 * ds; op[4] = o4 * ds;
    }
    __syncthreads();
    // pack phase: 640 u32 words (32 nodes x 20)
    for (int i = tid; i < 32 * 20; i += 256) {
        int n3 = i / 20, c3 = i % 20;
        const float* op = outs + n3 * N_CLASS + 2 * c3;
        h2b[(size_t)(blockIdx.x * 32 + n3) * 20 + c3] = cvtpk(op[0], op[1]);
    }
}

// ---------------- layer-2 gather + log_softmax: 8-lane group per node (5 active) ----------------
__global__ __launch_bounds__(256) void gather2_kernel(const unsigned* __restrict__ h2b,
                                                      const unsigned* __restrict__ rowmeta,
                                                      const int* __restrict__ csr_src,
                                                      const float* __restrict__ dis,
                                                      const float* __restrict__ b2,
                                                      float* __restrict__ xout,
                                                      float* __restrict__ out_ls) {
    int tid = threadIdx.x;
    int n = blockIdx.x * 32 + (tid >> 3);
    int l = tid & 7;
    bool act = l < 5;                      // lane owns classes 8l..8l+7 (l<5)
    unsigned meta = rowmeta[n];
    int base = (int)(meta & 0x7FFFFFu);
    int deg = (int)(meta >> 23);
    const unsigned* rowp = h2b + 4 * l;
    float a0 = 0.f, a1 = 0.f, a2 = 0.f, a3 = 0.f, a4 = 0.f, a5 = 0.f, a6 = 0.f, a7 = 0.f;
    if (act) {
        uint4 v = *reinterpret_cast<const uint4*>(h2b + (size_t)n * 20 + 4 * l);
        a0 = bflo(v.x); a1 = bfhi(v.x); a2 = bflo(v.y); a3 = bfhi(v.y);
        a4 = bflo(v.z); a5 = bfhi(v.z); a6 = bflo(v.w); a7 = bfhi(v.w);
    }
    int e = 0;
    for (; e + 7 < deg; e += 8) {
        int s0 = csr_src[base + e],     s1 = csr_src[base + e + 1];
        int s2 = csr_src[base + e + 2], s3 = csr_src[base + e + 3];
        int s4 = csr_src[base + e + 4], s5 = csr_src[base + e + 5];
        int s6 = csr_src[base + e + 6], s7 = csr_src[base + e + 7];
        if (act) {
            uint4 r0 = *reinterpret_cast<const uint4*>(rowp + (size_t)s0 * 20);
            uint4 r1 = *reinterpret_cast<const uint4*>(rowp + (size_t)s1 * 20);
            uint4 r2 = *reinterpret_cast<const uint4*>(rowp + (size_t)s2 * 20);
            uint4 r3 = *reinterpret_cast<const uint4*>(rowp + (size_t)s3 * 20);
            uint4 r4 = *reinterpret_cast<const uint4*>(rowp + (size_t)s4 * 20);
            uint4 r5 = *reinterpret_cast<const uint4*>(rowp + (size_t)s5 * 20);
            uint4 r6 = *reinterpret_cast<const uint4*>(rowp + (size_t)s6 * 20);
            uint4 r7 = *reinterpret_cast<const uint4*>(rowp + (size_t)s7 * 20);
            a0 += ((bflo(r0.x) + bflo(r1.x)) + (bflo(r2.x) + bflo(r3.x))) +
                  ((bflo(r4.x) + bflo(r5.x)) + (bflo(r6.x) + bflo(r7.x)));
            a1 += ((bfhi(r0.x) + bfhi(r1.x)) + (bfhi(r2.x) + bfhi(r3.x))) +
                  ((bfhi(r4.x) + bfhi(r5.x)) + (bfhi(r6.x) + bfhi(r7.x)));
            a2 += ((bflo(r0.y) + bflo(r1.y)) + (bflo(r2.y) + bflo(r3.y))) +
                  ((bflo(r4.y) + bflo(r5.y)) + (bflo(r6.y) + bflo(r7.y)));
            a3 += ((bfhi(r0.y) + bfhi(r1.y)) + (bfhi(r2.y) + bfhi(r3.y))) +
                  ((bfhi(r4.y) + bfhi(r5.y)) + (bfhi(r6.y) + bfhi(r7.y)));
            a4 += ((bflo(r0.z) + bflo(r1.z)) + (bflo(r2.z) + bflo(r3.z))) +
                  ((bflo(r4.z) + bflo(r5.z)) + (bflo(r6.z) + bflo(r7.z)));
            a5 += ((bfhi(r0.z) + bfhi(r1.z)) + (bfhi(r2.z) + bfhi(r3.z))) +
                  ((bfhi(r4.z) + bfhi(r5.z)) + (bfhi(r6.z) + bfhi(r7.z)));
            a6 += ((bflo(r0.w) + bflo(r1.w)) + (bflo(r2.w) + bflo(r3.w))) +
                  ((bflo(r4.w) + bflo(r5.w)) + (bflo(r6.w) + bflo(r7.w)));
            a7 += ((bfhi(r0.w) + bfhi(r1.w)) + (bfhi(r2.w) + bfhi(r3.w))) +
                  ((bfhi(r4.w) + bfhi(r5.w)) + (bfhi(r6.w) + bfhi(r7.w)));
        }
    }
    for (; e < deg; ++e) {
        int s = csr_src[base + e];
        if (act) {
            uint4 r = *reinterpret_cast<const uint4*>(rowp + (size_t)s * 20);
            a0 += bflo(r.x); a1 += bfhi(r.x); a2 += bflo(r.y); a3 += bfhi(r.y);
            a4 += bflo(r.z); a5 += bfhi(r.z); a6 += bflo(r.w); a7 += bfhi(r.w);
        }
    }
    float ds = dis[n];
    float v0 = 0.f, v1 = 0.f, v2 = 0.f, v3 = 0.f, v4 = 0.f, v5 = 0.f, v6 = 0.f, v7 = 0.f;
    if (act) {
        float4 bL = *reinterpret_cast<const float4*>(b2 + 8 * l);
        float4 bH = *reinterpret_cast<const float4*>(b2 + 8 * l + 4);
        v0 = fmaf(a0, ds, bL.x); v1 = fmaf(a1, ds, bL.y);
        v2 = fmaf(a2, ds, bL.z); v3 = fmaf(a3, ds, bL.w);
        v4 = fmaf(a4, ds, bH.x); v5 = fmaf(a5, ds, bH.y);
        v6 = fmaf(a6, ds, bH.z); v7 = fmaf(a7, ds, bH.w);
    }
    float mx = act ? fmaxf(fmaxf(fmaxf(v0, v1), fmaxf(v2, v3)),
                           fmaxf(fmaxf(v4, v5), fmaxf(v6, v7))) : -INFINITY;
    mx = fmaxf(mx, __shfl_xor(mx, 1));
    mx = fmaxf(mx, __shfl_xor(mx, 2));
    mx = fmaxf(mx, __shfl_xor(mx, 4));
    float sum = act ? ((expf(v0 - mx) + expf(v1 - mx)) + (expf(v2 - mx) + expf(v3 - mx))) +
                      ((expf(v4 - mx) + expf(v5 - mx)) + (expf(v6 - mx) + expf(v7 - mx))) : 0.f;
    sum += __shfl_xor(sum, 1);
    sum += __shfl_xor(sum, 2);
    sum += __shfl_xor(sum, 4);
    if (act) {
        float ls = mx + logf(sum);
        float* xp = xout + (size_t)n * N_CLASS + 8 * l;
        float* lp = out_ls + (size_t)n * N_CLASS + 8 * l;
        float4 xoL = {v0, v1, v2, v3};
        float4 xoH = {v4, v5, v6, v7};
        float4 loL = {v0 - ls, v1 - ls, v2 - ls, v3 - ls};
        float4 loH = {v4 - ls, v5 - ls, v6 - ls, v7 - ls};
        *reinterpret_cast<float4*>(xp) = xoL;
        *reinterpret_cast<float4*>(xp + 4) = xoH;
        *reinterpret_cast<float4*>(lp) = loL;
        *reinterpret_cast<float4*>(lp + 4) = loH;
    }
}

extern "C" void kernel_launch(void* const* d_in, const int* in_sizes, int n_in,
                              void* d_out, int out_size, void* d_ws, size_t ws_size,
                              hipStream_t stream) {
    const float* x  = (const float*)d_in[0];
    const EIdx*  ei = (const EIdx*)d_in[1];
    const float* W1 = (const float*)d_in[2];
    const float* b1 = (const float*)d_in[3];
    const float* W2 = (const float*)d_in[4];
    const float* b2 = (const float*)d_in[5];
    const EIdx* src = ei;
    const EIdx* dst = ei + N_EDGES;

    float* out_ls = (float*)d_out;                        // [N, 40] log_softmax
    float* x_out  = out_ls + (size_t)N_NODES * N_CLASS;   // [N, 40]

    char* w = (char*)d_ws;
    int*      bcur    = (int*)w;       w += 1024 * 4;
    float*    dis     = (float*)w;     w += 100352 * 4;
    unsigned* rowmeta = (unsigned*)w;  w += 100352 * 4;
    short*    Wbf     = (short*)w;     w += (size_t)F_IN * HIDDEN * 2;
    // bpacked (part1->part2) aliases h1b (written by gemm1, which runs after part2)
    unsigned* bpacked = (unsigned*)w;
    unsigned* h1b     = (unsigned*)w;  w += (size_t)NB * CAP * 4;        // 19.2MB >= N*32*4
    int*      csr_src = (int*)w;       w += (size_t)NB * CAP * 4;
    unsigned* h2b     = (unsigned*)w;  w += (size_t)N_NODES * 20 * 4;    // bf16-packed [N][20]

    const int B = 256;
    int gG  = N_NODES / 32;              // 3125 (8-lane group per node)
    int gM1 = (N_NODES + 127) / 128;     // 782

    // W prep + bucket cursor init, then CSR build
    wprep_kernel<<<(F_IN * HIDDEN) / B, B, 0, stream>>>(W1, Wbf, bcur);
    part1_kernel<<<NPB, B, 0, stream>>>(src, dst, bcur, bpacked);
    part2_kernel<<<NB, B, 0, stream>>>(bcur, bpacked, csr_src, rowmeta, dis);

    // layer 1 (+ fused layer-2 linear)
    gemm1_mfma_kernel<<<gM1, B, 0, stream>>>(x, Wbf, dis, h1b);
    gather1_gemm2_kernel<<<gG, B, 0, stream>>>(h1b, rowmeta, csr_src, dis, b1, W2, h2b);

    // layer 2 aggregation + log_softmax
    gather2_kernel<<<gG, B, 0, stream>>>(h2b, rowmeta, csr_src, dis, b2, x_out, out_ls);
}